// Round 1
// baseline (2000.245 us; speedup 1.0000x reference)
//
#include <hip/hip_runtime.h>
#include <math.h>
#include <float.h>
#include <stdint.h>

#define B_ 4
#define N_ 8192
#define K_ 9
#define NPTS (B_ * N_)          // 32768
#define NROWS (NPTS * K_)       // 294912
#define KNN_BLOCKS (NPTS / 64)  // 512
#define MLP_BLOCKS (NROWS / 256) // 1152

// ---------------- K0: pack x (B,N,3) -> SoA X,Y,Z and squared norms S ----------
__launch_bounds__(256)
__global__ void k_pack(const float* __restrict__ x, float* __restrict__ X,
                       float* __restrict__ Y, float* __restrict__ Z,
                       float* __restrict__ S) {
  int i = blockIdx.x * 256 + threadIdx.x;
  if (i >= NPTS) return;
  float a = x[3 * i], b = x[3 * i + 1], c = x[3 * i + 2];
  X[i] = a; Y[i] = b; Z[i] = c;
  S[i] = a * a + b * b + c * c;
}

// ---------------- K1: KNN + geometric features + h1 = feat@W1+b1 + stats partials
__launch_bounds__(64)
__global__ void k_knn(const float* __restrict__ X, const float* __restrict__ Y,
                      const float* __restrict__ Z, const float* __restrict__ S,
                      const float* __restrict__ W1, const float* __restrict__ b1,
                      float* __restrict__ h1, double* __restrict__ part1) {
  int p = blockIdx.x * 64 + threadIdx.x;     // global point id
  int b = p >> 13;                            // / 8192
  int n = p & (N_ - 1);
  const float* __restrict__ Xb = X + b * N_;
  const float* __restrict__ Yb = Y + b * N_;
  const float* __restrict__ Zb = Z + b * N_;
  const float* __restrict__ Sb = S + b * N_;

  float qx = Xb[n], qy = Yb[n], qz = Zb[n], qs = Sb[n];

  // top-9 nearest (excluding self), kept sorted ascending by distance.
  float bd[K_]; int bi[K_];
#pragma unroll
  for (int t = 0; t < K_; ++t) { bd[t] = FLT_MAX; bi[t] = 0; }

  for (int j = 0; j < N_; ++j) {
    // j is wave-uniform -> candidate data via scalar loads
    float cx = Xb[j], cy = Yb[j], cz = Zb[j], cs = Sb[j];
    float dot = qx * cx + qy * cy + qz * cz;
    float d2 = (qs + cs) - 2.0f * dot;
    d2 = (j == n) ? FLT_MAX : d2;   // exclude self
    if (d2 < bd[K_ - 1]) {
      float cd = d2; int ci = j;
#pragma unroll
      for (int t = 0; t < K_; ++t) {
        if (cd < bd[t]) {
          float td = bd[t]; int ti = bi[t];
          bd[t] = cd; bi[t] = ci;
          cd = td; ci = ti;
        }
      }
    }
  }

  // relative vectors in distance order (matches reference pre-sort order)
  float rx[K_], ry[K_], rz[K_], ph[K_];
#pragma unroll
  for (int t = 0; t < K_; ++t) {
    int m = bi[t];
    rx[t] = Xb[m] - qx;
    ry[t] = Yb[m] - qy;
    rz[t] = Zb[m] - qz;
    ph[t] = atan2f(ry[t], rx[t]);
  }

  // stable insertion sort (unrolled, static indices -> registers) ascending by phi
#pragma unroll
  for (int i = 1; i < K_; ++i) {
#pragma unroll
    for (int j2 = i; j2 > 0; --j2) {
      if (ph[j2] < ph[j2 - 1]) {
        float t0;
        t0 = ph[j2]; ph[j2] = ph[j2 - 1]; ph[j2 - 1] = t0;
        t0 = rx[j2]; rx[j2] = rx[j2 - 1]; rx[j2 - 1] = t0;
        t0 = ry[j2]; ry[j2] = ry[j2 - 1]; ry[j2 - 1] = t0;
        t0 = rz[j2]; rz[j2] = rz[j2 - 1]; rz[j2 - 1] = t0;
      }
    }
  }

  double sum[10], ss[10];
#pragma unroll
  for (int c = 0; c < 10; ++c) { sum[c] = 0.0; ss[c] = 0.0; }

  float sgn = 1.0f;
#pragma unroll
  for (int t = 0; t < K_; ++t) {
    int u = (t + 1 == K_) ? 0 : t + 1;
    float cx = 0.5f * (rx[t] + rx[u]);
    float cy = 0.5f * (ry[t] + ry[u]);
    float cz = 0.5f * (rz[t] + rz[u]);
    float nx = ry[t] * rz[u] - rz[t] * ry[u];
    float ny = rz[t] * rx[u] - rx[t] * rz[u];
    float nz = rx[t] * ry[u] - ry[t] * rx[u];
    float nrm = sqrtf(nx * nx + ny * ny + nz * nz) + 1e-6f;
    nx /= nrm; ny /= nrm; nz /= nrm;
    if (t == 0) sgn = (nx > 0.0f) ? 1.0f : -1.0f;
    nx *= sgn; ny *= sgn; nz *= sgn;
    float pos = (nx * cx + ny * cy + nz * cz) / 1.7320508075688772f;

    float fv[7] = {cx, cy, cz, nx, ny, nz, pos};
    size_t row = ((size_t)p * K_ + t) * 10;
#pragma unroll
    for (int c = 0; c < 10; ++c) {
      float h = b1[c];
#pragma unroll
      for (int r = 0; r < 7; ++r) h = fmaf(fv[r], W1[r * 10 + c], h);
      h1[row + c] = h;
      double hd = (double)h;
      sum[c] += hd;
      ss[c] += hd * hd;
    }
  }

  // wave-level fp64 reduction -> per-block partials
#pragma unroll
  for (int c = 0; c < 10; ++c) {
    double a = sum[c];
#pragma unroll
    for (int off = 32; off > 0; off >>= 1) a += __shfl_down(a, off);
    if (threadIdx.x == 0) part1[(size_t)blockIdx.x * 20 + c] = a;
    double q = ss[c];
#pragma unroll
    for (int off = 32; off > 0; off >>= 1) q += __shfl_down(q, off);
    if (threadIdx.x == 0) part1[(size_t)blockIdx.x * 20 + 10 + c] = q;
  }
}

// ---------------- K2: reduce partials -> mu[10], rsqrt(var+eps)[10] -------------
__launch_bounds__(256)
__global__ void k_reduce(const double* __restrict__ part, int nblk,
                         float* __restrict__ MR) {
  __shared__ double acc[256];
  int tid = threadIdx.x;
  int c = tid % 20;
  int ch = tid / 20;
  double s = 0.0;
  if (ch < 12) {
    for (int i = ch; i < nblk; i += 12) s += part[(size_t)i * 20 + c];
  }
  acc[tid] = s;
  __syncthreads();
  if (tid < 20) {
    double t = 0.0;
#pragma unroll
    for (int k2 = 0; k2 < 12; ++k2) t += acc[k2 * 20 + tid];
    acc[tid] = t;
  }
  __syncthreads();
  if (tid < 10) {
    double mu = acc[tid] / (double)NROWS;
    double var = acc[10 + tid] / (double)NROWS - mu * mu;
    MR[tid] = (float)mu;
    MR[10 + tid] = (float)(1.0 / sqrt(var + 1e-5));
  }
}

// ---------------- K3: bn1 + relu + @W2+b2 -> h2, stats partials -----------------
__launch_bounds__(256)
__global__ void k_mlp2(const float* __restrict__ h1, const float* __restrict__ MR1,
                       const float* __restrict__ g1, const float* __restrict__ be1,
                       const float* __restrict__ W2, const float* __restrict__ b2,
                       float* __restrict__ h2, double* __restrict__ part2) {
  int r = blockIdx.x * 256 + threadIdx.x;   // grid sized exactly
  float v[10];
#pragma unroll
  for (int c = 0; c < 10; ++c) {
    float h = h1[(size_t)r * 10 + c];
    float z = g1[c] * (h - MR1[c]) * MR1[10 + c] + be1[c];
    v[c] = z > 0.0f ? z : 0.0f;
  }
  float o[10];
#pragma unroll
  for (int c = 0; c < 10; ++c) {
    float h = b2[c];
#pragma unroll
    for (int t = 0; t < 10; ++t) h = fmaf(v[t], W2[t * 10 + c], h);
    o[c] = h;
    h2[(size_t)r * 10 + c] = h;
  }

  __shared__ double sred[4][20];
  int lane = threadIdx.x & 63, wv = threadIdx.x >> 6;
#pragma unroll
  for (int c = 0; c < 10; ++c) {
    double a = (double)o[c];
#pragma unroll
    for (int off = 32; off > 0; off >>= 1) a += __shfl_down(a, off);
    if (lane == 0) sred[wv][c] = a;
    double q = (double)o[c] * (double)o[c];
#pragma unroll
    for (int off = 32; off > 0; off >>= 1) q += __shfl_down(q, off);
    if (lane == 0) sred[wv][10 + c] = q;
  }
  __syncthreads();
  if (threadIdx.x < 20) {
    part2[(size_t)blockIdx.x * 20 + threadIdx.x] =
        sred[0][threadIdx.x] + sred[1][threadIdx.x] +
        sred[2][threadIdx.x] + sred[3][threadIdx.x];
  }
}

// ---------------- K4: bn2 + relu + max over k -> out ----------------------------
__launch_bounds__(256)
__global__ void k_out(const float* __restrict__ h2, const float* __restrict__ MR2,
                      const float* __restrict__ g2, const float* __restrict__ be2,
                      float* __restrict__ out) {
  int p = blockIdx.x * 256 + threadIdx.x;
  if (p >= NPTS) return;
#pragma unroll
  for (int c = 0; c < 10; ++c) {
    float m = -FLT_MAX;
#pragma unroll
    for (int j = 0; j < K_; ++j) {
      float h = h2[((size_t)p * K_ + j) * 10 + c];
      float z = g2[c] * (h - MR2[c]) * MR2[10 + c] + be2[c];
      z = z > 0.0f ? z : 0.0f;
      m = fmaxf(m, z);
    }
    out[(size_t)p * 10 + c] = m;
  }
}

extern "C" void kernel_launch(void* const* d_in, const int* in_sizes, int n_in,
                              void* d_out, int out_size, void* d_ws, size_t ws_size,
                              hipStream_t stream) {
  (void)in_sizes; (void)n_in; (void)out_size; (void)ws_size;
  const float* x  = (const float*)d_in[0];
  const float* W1 = (const float*)d_in[1];
  const float* b1 = (const float*)d_in[2];
  const float* g1 = (const float*)d_in[3];
  const float* be1= (const float*)d_in[4];
  const float* W2 = (const float*)d_in[5];
  const float* b2 = (const float*)d_in[6];
  const float* g2 = (const float*)d_in[7];
  const float* be2= (const float*)d_in[8];
  float* out = (float*)d_out;

  float* X  = (float*)d_ws;
  float* Y  = X + NPTS;
  float* Z  = Y + NPTS;
  float* S  = Z + NPTS;
  float* h1 = S + NPTS;                       // NROWS*10 floats
  float* h2 = h1 + (size_t)NROWS * 10;        // NROWS*10 floats
  float* MR1 = h2 + (size_t)NROWS * 10;       // 20 floats (pad to 32)
  float* MR2 = MR1 + 32;
  uintptr_t pa = ((uintptr_t)(MR2 + 32) + 15) & ~(uintptr_t)15;
  double* part1 = (double*)pa;                // 512*20 doubles
  double* part2 = part1 + (size_t)KNN_BLOCKS * 20; // 1152*20 doubles

  k_pack<<<(NPTS + 255) / 256, 256, 0, stream>>>(x, X, Y, Z, S);
  k_knn<<<KNN_BLOCKS, 64, 0, stream>>>(X, Y, Z, S, W1, b1, h1, part1);
  k_reduce<<<1, 256, 0, stream>>>(part1, KNN_BLOCKS, MR1);
  k_mlp2<<<MLP_BLOCKS, 256, 0, stream>>>(h1, MR1, g1, be1, W2, b2, h2, part2);
  k_reduce<<<1, 256, 0, stream>>>(part2, MLP_BLOCKS, MR2);
  k_out<<<(NPTS + 255) / 256, 256, 0, stream>>>(h2, MR2, g2, be2, out);
}

// Round 2
// 1086.732 us; speedup vs baseline: 1.8406x; 1.8406x over previous
//
#include <hip/hip_runtime.h>
#include <math.h>
#include <float.h>
#include <stdint.h>

#define B_ 4
#define N_ 8192
#define K_ 9
#define NPTS (B_ * N_)           // 32768
#define NROWS (NPTS * K_)        // 294912
#define SPLIT 8
#define CHUNK (N_ / SPLIT)       // 1024
#define PT_BLOCKS (NPTS / 64)    // 512
#define MLP_BLOCKS (NROWS / 256) // 1152

// ---------------- K0: pack x (B,N,3) -> float4 (x,y,z,|x|^2) -------------------
__launch_bounds__(256)
__global__ void k_pack(const float* __restrict__ x, float4* __restrict__ P) {
  int i = blockIdx.x * 256 + threadIdx.x;
  if (i >= NPTS) return;
  float a = x[3 * i], b = x[3 * i + 1], c = x[3 * i + 2];
  P[i] = make_float4(a, b, c, a * a + b * b + c * c);
}

__device__ __forceinline__ void ins9(float (&bd)[K_], int (&bi)[K_], float cd, int ci) {
#pragma unroll
  for (int t = 0; t < K_; ++t) {
    if (cd < bd[t]) {
      float td = bd[t]; int ti = bi[t];
      bd[t] = cd; bi[t] = ci;
      cd = td; ci = ti;
    }
  }
}

// ---------------- K1: partial KNN — each block scans one 1024-candidate chunk ---
__launch_bounds__(64)
__global__ void k_knn_part(const float4* __restrict__ P,
                           float* __restrict__ pbd, int* __restrict__ pbi) {
  int pt_blk = blockIdx.x >> 3;          // / SPLIT
  int s = blockIdx.x & (SPLIT - 1);
  int p = pt_blk * 64 + threadIdx.x;
  int b = p >> 13;
  int n = p & (N_ - 1);
  const float4* __restrict__ Pb = P + b * N_;

  float4 q = Pb[n];
  float bd[K_]; int bi[K_];
#pragma unroll
  for (int t = 0; t < K_; ++t) { bd[t] = FLT_MAX; bi[t] = 0; }

  int j0 = s * CHUNK;
  for (int j = j0; j < j0 + CHUNK; j += 4) {
    float4 c0 = Pb[j];
    float4 c1 = Pb[j + 1];
    float4 c2 = Pb[j + 2];
    float4 c3 = Pb[j + 3];
    float d0 = (q.w + c0.w) - 2.0f * (q.x * c0.x + q.y * c0.y + q.z * c0.z);
    float d1 = (q.w + c1.w) - 2.0f * (q.x * c1.x + q.y * c1.y + q.z * c1.z);
    float d2 = (q.w + c2.w) - 2.0f * (q.x * c2.x + q.y * c2.y + q.z * c2.z);
    float d3 = (q.w + c3.w) - 2.0f * (q.x * c3.x + q.y * c3.y + q.z * c3.z);
    if (j + 0 == n) d0 = FLT_MAX;
    if (j + 1 == n) d1 = FLT_MAX;
    if (j + 2 == n) d2 = FLT_MAX;
    if (j + 3 == n) d3 = FLT_MAX;
    float gm = fminf(fminf(d0, d1), fminf(d2, d3));
    if (gm < bd[K_ - 1]) {
      if (d0 < bd[K_ - 1]) ins9(bd, bi, d0, j);
      if (d1 < bd[K_ - 1]) ins9(bd, bi, d1, j + 1);
      if (d2 < bd[K_ - 1]) ins9(bd, bi, d2, j + 2);
      if (d3 < bd[K_ - 1]) ins9(bd, bi, d3, j + 3);
    }
  }

  float* ob = pbd + ((size_t)p * SPLIT + s) * K_;
  int*   oi = pbi + ((size_t)p * SPLIT + s) * K_;
#pragma unroll
  for (int t = 0; t < K_; ++t) { ob[t] = bd[t]; oi[t] = bi[t]; }
}

// ---------------- K2: merge partials + geometric features + h1 + stats ----------
__launch_bounds__(64)
__global__ void k_feat(const float4* __restrict__ P,
                       const float* __restrict__ pbd, const int* __restrict__ pbi,
                       const float* __restrict__ W1, const float* __restrict__ b1,
                       float* __restrict__ h1, double* __restrict__ part1) {
  int p = blockIdx.x * 64 + threadIdx.x;
  int b = p >> 13;
  int n = p & (N_ - 1);
  const float4* __restrict__ Pb = P + b * N_;
  float4 q = Pb[n];

  // merge 8 sorted partial lists (ascending chunk order = ascending index order
  // -> stable strict-< insertion reproduces top_k tie-breaking)
  float bd[K_]; int bi[K_];
#pragma unroll
  for (int t = 0; t < K_; ++t) { bd[t] = FLT_MAX; bi[t] = 0; }
  const float* mb = pbd + (size_t)p * (SPLIT * K_);
  const int*   ib = pbi + (size_t)p * (SPLIT * K_);
#pragma unroll
  for (int s = 0; s < SPLIT * K_; ++s) {
    float cd = mb[s];
    if (cd < bd[K_ - 1]) ins9(bd, bi, cd, ib[s]);
  }

  // relative vectors in distance order (reference pre-sort order)
  float rx[K_], ry[K_], rz[K_], ph[K_];
#pragma unroll
  for (int t = 0; t < K_; ++t) {
    float4 m = Pb[bi[t]];
    rx[t] = m.x - q.x;
    ry[t] = m.y - q.y;
    rz[t] = m.z - q.z;
    ph[t] = atan2f(ry[t], rx[t]);
  }

  // stable insertion sort ascending by phi
#pragma unroll
  for (int i = 1; i < K_; ++i) {
#pragma unroll
    for (int j2 = i; j2 > 0; --j2) {
      if (ph[j2] < ph[j2 - 1]) {
        float t0;
        t0 = ph[j2]; ph[j2] = ph[j2 - 1]; ph[j2 - 1] = t0;
        t0 = rx[j2]; rx[j2] = rx[j2 - 1]; rx[j2 - 1] = t0;
        t0 = ry[j2]; ry[j2] = ry[j2 - 1]; ry[j2 - 1] = t0;
        t0 = rz[j2]; rz[j2] = rz[j2 - 1]; rz[j2 - 1] = t0;
      }
    }
  }

  double sum[10], ss[10];
#pragma unroll
  for (int c = 0; c < 10; ++c) { sum[c] = 0.0; ss[c] = 0.0; }

  float sgn = 1.0f;
#pragma unroll
  for (int t = 0; t < K_; ++t) {
    int u = (t + 1 == K_) ? 0 : t + 1;
    float cx = 0.5f * (rx[t] + rx[u]);
    float cy = 0.5f * (ry[t] + ry[u]);
    float cz = 0.5f * (rz[t] + rz[u]);
    float nx = ry[t] * rz[u] - rz[t] * ry[u];
    float ny = rz[t] * rx[u] - rx[t] * rz[u];
    float nz = rx[t] * ry[u] - ry[t] * rx[u];
    float nrm = sqrtf(nx * nx + ny * ny + nz * nz) + 1e-6f;
    nx /= nrm; ny /= nrm; nz /= nrm;
    if (t == 0) sgn = (nx > 0.0f) ? 1.0f : -1.0f;
    nx *= sgn; ny *= sgn; nz *= sgn;
    float pos = (nx * cx + ny * cy + nz * cz) / 1.7320508075688772f;

    float fv[7] = {cx, cy, cz, nx, ny, nz, pos};
    size_t row = ((size_t)p * K_ + t) * 10;
#pragma unroll
    for (int c = 0; c < 10; ++c) {
      float h = b1[c];
#pragma unroll
      for (int r = 0; r < 7; ++r) h = fmaf(fv[r], W1[r * 10 + c], h);
      h1[row + c] = h;
      double hd = (double)h;
      sum[c] += hd;
      ss[c] += hd * hd;
    }
  }

#pragma unroll
  for (int c = 0; c < 10; ++c) {
    double a = sum[c];
#pragma unroll
    for (int off = 32; off > 0; off >>= 1) a += __shfl_down(a, off);
    if (threadIdx.x == 0) part1[(size_t)blockIdx.x * 20 + c] = a;
    double qq = ss[c];
#pragma unroll
    for (int off = 32; off > 0; off >>= 1) qq += __shfl_down(qq, off);
    if (threadIdx.x == 0) part1[(size_t)blockIdx.x * 20 + 10 + c] = qq;
  }
}

// ---------------- K3: reduce partials -> mu[10], rsqrt(var+eps)[10] -------------
__launch_bounds__(256)
__global__ void k_reduce(const double* __restrict__ part, int nblk,
                         float* __restrict__ MR) {
  __shared__ double acc[256];
  int tid = threadIdx.x;
  int c = tid % 20;
  int ch = tid / 20;
  double s = 0.0;
  if (ch < 12) {
    for (int i = ch; i < nblk; i += 12) s += part[(size_t)i * 20 + c];
  }
  acc[tid] = s;
  __syncthreads();
  if (tid < 20) {
    double t = 0.0;
#pragma unroll
    for (int k2 = 0; k2 < 12; ++k2) t += acc[k2 * 20 + tid];
    acc[tid] = t;
  }
  __syncthreads();
  if (tid < 10) {
    double mu = acc[tid] / (double)NROWS;
    double var = acc[10 + tid] / (double)NROWS - mu * mu;
    MR[tid] = (float)mu;
    MR[10 + tid] = (float)(1.0 / sqrt(var + 1e-5));
  }
}

// ---------------- K4: bn1 + relu + @W2+b2 -> h2, stats partials -----------------
__launch_bounds__(256)
__global__ void k_mlp2(const float* __restrict__ h1, const float* __restrict__ MR1,
                       const float* __restrict__ g1, const float* __restrict__ be1,
                       const float* __restrict__ W2, const float* __restrict__ b2,
                       float* __restrict__ h2, double* __restrict__ part2) {
  int r = blockIdx.x * 256 + threadIdx.x;
  float v[10];
#pragma unroll
  for (int c = 0; c < 10; ++c) {
    float h = h1[(size_t)r * 10 + c];
    float z = g1[c] * (h - MR1[c]) * MR1[10 + c] + be1[c];
    v[c] = z > 0.0f ? z : 0.0f;
  }
  float o[10];
#pragma unroll
  for (int c = 0; c < 10; ++c) {
    float h = b2[c];
#pragma unroll
    for (int t = 0; t < 10; ++t) h = fmaf(v[t], W2[t * 10 + c], h);
    o[c] = h;
    h2[(size_t)r * 10 + c] = h;
  }

  __shared__ double sred[4][20];
  int lane = threadIdx.x & 63, wv = threadIdx.x >> 6;
#pragma unroll
  for (int c = 0; c < 10; ++c) {
    double a = (double)o[c];
#pragma unroll
    for (int off = 32; off > 0; off >>= 1) a += __shfl_down(a, off);
    if (lane == 0) sred[wv][c] = a;
    double qq = (double)o[c] * (double)o[c];
#pragma unroll
    for (int off = 32; off > 0; off >>= 1) qq += __shfl_down(qq, off);
    if (lane == 0) sred[wv][10 + c] = qq;
  }
  __syncthreads();
  if (threadIdx.x < 20) {
    part2[(size_t)blockIdx.x * 20 + threadIdx.x] =
        sred[0][threadIdx.x] + sred[1][threadIdx.x] +
        sred[2][threadIdx.x] + sred[3][threadIdx.x];
  }
}

// ---------------- K5: bn2 + relu + max over k -> out ----------------------------
__launch_bounds__(256)
__global__ void k_out(const float* __restrict__ h2, const float* __restrict__ MR2,
                      const float* __restrict__ g2, const float* __restrict__ be2,
                      float* __restrict__ out) {
  int p = blockIdx.x * 256 + threadIdx.x;
  if (p >= NPTS) return;
#pragma unroll
  for (int c = 0; c < 10; ++c) {
    float m = -FLT_MAX;
#pragma unroll
    for (int j = 0; j < K_; ++j) {
      float h = h2[((size_t)p * K_ + j) * 10 + c];
      float z = g2[c] * (h - MR2[c]) * MR2[10 + c] + be2[c];
      z = z > 0.0f ? z : 0.0f;
      m = fmaxf(m, z);
    }
    out[(size_t)p * 10 + c] = m;
  }
}

extern "C" void kernel_launch(void* const* d_in, const int* in_sizes, int n_in,
                              void* d_out, int out_size, void* d_ws, size_t ws_size,
                              hipStream_t stream) {
  (void)in_sizes; (void)n_in; (void)out_size; (void)ws_size;
  const float* x  = (const float*)d_in[0];
  const float* W1 = (const float*)d_in[1];
  const float* b1 = (const float*)d_in[2];
  const float* g1 = (const float*)d_in[3];
  const float* be1= (const float*)d_in[4];
  const float* W2 = (const float*)d_in[5];
  const float* b2 = (const float*)d_in[6];
  const float* g2 = (const float*)d_in[7];
  const float* be2= (const float*)d_in[8];
  float* out = (float*)d_out;

  char* base = (char*)d_ws;
  float4* P  = (float4*)base;                       // 512 KB
  float*  h1 = (float*)(base + (size_t)NPTS * 16);  // 11.8 MB
  char*   C  = (char*)(h1 + (size_t)NROWS * 10);
  float*  pbd = (float*)C;                          // 9.44 MB
  int*    pbi = (int*)(C + (size_t)NPTS * SPLIT * K_ * 4);  // 9.44 MB
  // h2/part2 alias the pbd/pbi region (pbd/pbi fully consumed by k_feat
  // before k_mlp2 writes h2)
  float*  h2 = (float*)C;                           // 11.8 MB
  double* part2 = (double*)(C + 12 * 1024 * 1024);  // 184 KB, within C's 18.9MB
  char*   tail = C + (size_t)NPTS * SPLIT * K_ * 8;
  float*  MR1 = (float*)tail;
  float*  MR2 = MR1 + 32;
  double* part1 = (double*)(MR2 + 32);              // 512*20 doubles

  k_pack<<<(NPTS + 255) / 256, 256, 0, stream>>>(x, P);
  k_knn_part<<<PT_BLOCKS * SPLIT, 64, 0, stream>>>(P, pbd, pbi);
  k_feat<<<PT_BLOCKS, 64, 0, stream>>>(P, pbd, pbi, W1, b1, h1, part1);
  k_reduce<<<1, 256, 0, stream>>>(part1, PT_BLOCKS, MR1);
  k_mlp2<<<MLP_BLOCKS, 256, 0, stream>>>(h1, MR1, g1, be1, W2, b2, h2, part2);
  k_reduce<<<1, 256, 0, stream>>>(part2, MLP_BLOCKS, MR2);
  k_out<<<(NPTS + 255) / 256, 256, 0, stream>>>(h2, MR2, g2, be2, out);
}

// Round 3
// 556.457 us; speedup vs baseline: 3.5946x; 1.9529x over previous
//
#include <hip/hip_runtime.h>
#include <math.h>
#include <float.h>
#include <stdint.h>

#define B_ 4
#define N_ 8192
#define K_ 9
#define NPTS (B_ * N_)           // 32768
#define NROWS (NPTS * K_)        // 294912
#define SPLIT 8
#define CHUNK (N_ / SPLIT)       // 1024
#define PT_BLOCKS (NPTS / 64)    // 512
#define MLP_BLOCKS (NROWS / 256) // 1152

// ---------------- K0: pack x (B,N,3) -> float4 (x,y,z,|x|^2) -------------------
__launch_bounds__(256)
__global__ void k_pack(const float* __restrict__ x, float4* __restrict__ P) {
  int i = blockIdx.x * 256 + threadIdx.x;
  if (i >= NPTS) return;
  float a = x[3 * i], b = x[3 * i + 1], c = x[3 * i + 2];
  P[i] = make_float4(a, b, c, a * a + b * b + c * c);
}

// Register-resident sorted top-9 (ascending). One level of shift-insert:
// 1 cmp + 4 cndmask, all named scalars -> guaranteed VGPRs.
#define LVL(bdv, biv)                                                     \
  { bool lt = cd < (bdv); float td = (bdv); int ti = (biv);               \
    (bdv) = lt ? cd : (bdv); (biv) = lt ? ci : (biv);                     \
    cd = lt ? td : cd; ci = lt ? ti : ci; }

#define INS9ALL()                                                         \
  LVL(b0d, b0i) LVL(b1d, b1i) LVL(b2d, b2i) LVL(b3d, b3i) LVL(b4d, b4i)  \
  LVL(b5d, b5i) LVL(b6d, b6i) LVL(b7d, b7i) LVL(b8d, b8i)

#define TOP9_DECL()                                                       \
  float b0d = FLT_MAX, b1d = FLT_MAX, b2d = FLT_MAX, b3d = FLT_MAX,       \
        b4d = FLT_MAX, b5d = FLT_MAX, b6d = FLT_MAX, b7d = FLT_MAX,       \
        b8d = FLT_MAX;                                                    \
  int b0i = 0, b1i = 0, b2i = 0, b3i = 0, b4i = 0, b5i = 0, b6i = 0,      \
      b7i = 0, b8i = 0;

// ---------------- K1: partial KNN — each block scans one 1024-candidate chunk ---
__launch_bounds__(64)
__global__ void k_knn_part(const float4* __restrict__ P,
                           float* __restrict__ pbd, int* __restrict__ pbi) {
  int pt_blk = blockIdx.x >> 3;          // / SPLIT
  int s = blockIdx.x & (SPLIT - 1);
  int p = pt_blk * 64 + threadIdx.x;
  int b = p >> 13;
  int n = p & (N_ - 1);
  const float4* __restrict__ Pb = P + b * N_;

  float4 q = Pb[n];
  TOP9_DECL();

  int j0 = s * CHUNK;
  for (int j = j0; j < j0 + CHUNK; j += 4) {
    float4 c0 = Pb[j];
    float4 c1 = Pb[j + 1];
    float4 c2 = Pb[j + 2];
    float4 c3 = Pb[j + 3];
    float d0 = (q.w + c0.w) - 2.0f * (q.x * c0.x + q.y * c0.y + q.z * c0.z);
    float d1 = (q.w + c1.w) - 2.0f * (q.x * c1.x + q.y * c1.y + q.z * c1.z);
    float d2 = (q.w + c2.w) - 2.0f * (q.x * c2.x + q.y * c2.y + q.z * c2.z);
    float d3 = (q.w + c3.w) - 2.0f * (q.x * c3.x + q.y * c3.y + q.z * c3.z);
    if (j + 0 == n) d0 = FLT_MAX;
    if (j + 1 == n) d1 = FLT_MAX;
    if (j + 2 == n) d2 = FLT_MAX;
    if (j + 3 == n) d3 = FLT_MAX;
    float gm = fminf(fminf(d0, d1), fminf(d2, d3));
    if (gm < b8d) {
      if (d0 < b8d) { float cd = d0; int ci = j + 0; INS9ALL(); }
      if (d1 < b8d) { float cd = d1; int ci = j + 1; INS9ALL(); }
      if (d2 < b8d) { float cd = d2; int ci = j + 2; INS9ALL(); }
      if (d3 < b8d) { float cd = d3; int ci = j + 3; INS9ALL(); }
    }
  }

  float* ob = pbd + ((size_t)p * SPLIT + s) * K_;
  int*   oi = pbi + ((size_t)p * SPLIT + s) * K_;
  ob[0] = b0d; ob[1] = b1d; ob[2] = b2d; ob[3] = b3d; ob[4] = b4d;
  ob[5] = b5d; ob[6] = b6d; ob[7] = b7d; ob[8] = b8d;
  oi[0] = b0i; oi[1] = b1i; oi[2] = b2i; oi[3] = b3i; oi[4] = b4i;
  oi[5] = b5i; oi[6] = b6i; oi[7] = b7i; oi[8] = b8i;
}

// ---------------- K2: merge partials + geometric features + h1 + stats ----------
__launch_bounds__(64)
__global__ void k_feat(const float4* __restrict__ P,
                       const float* __restrict__ pbd, const int* __restrict__ pbi,
                       const float* __restrict__ W1, const float* __restrict__ b1,
                       float* __restrict__ h1, double* __restrict__ part1) {
  int p = blockIdx.x * 64 + threadIdx.x;
  int b = p >> 13;
  int n = p & (N_ - 1);
  const float4* __restrict__ Pb = P + b * N_;
  float4 q = Pb[n];

  // merge 8 sorted partial lists (ascending chunk order = ascending index order
  // -> stable strict-< insertion reproduces top_k tie-breaking)
  TOP9_DECL();
  const float* mb = pbd + (size_t)p * (SPLIT * K_);
  const int*   ib = pbi + (size_t)p * (SPLIT * K_);
  for (int s = 0; s < SPLIT * K_; ++s) {
    float cd = mb[s];
    if (cd < b8d) { int ci = ib[s]; INS9ALL(); }
  }

  int bi[K_] = {b0i, b1i, b2i, b3i, b4i, b5i, b6i, b7i, b8i};

  // relative vectors in distance order (reference pre-sort order)
  float rx[K_], ry[K_], rz[K_], ph[K_];
#pragma unroll
  for (int t = 0; t < K_; ++t) {
    float4 m = Pb[bi[t]];
    rx[t] = m.x - q.x;
    ry[t] = m.y - q.y;
    rz[t] = m.z - q.z;
    ph[t] = atan2f(ry[t], rx[t]);
  }

  // stable insertion sort ascending by phi
#pragma unroll
  for (int i = 1; i < K_; ++i) {
#pragma unroll
    for (int j2 = i; j2 > 0; --j2) {
      if (ph[j2] < ph[j2 - 1]) {
        float t0;
        t0 = ph[j2]; ph[j2] = ph[j2 - 1]; ph[j2 - 1] = t0;
        t0 = rx[j2]; rx[j2] = rx[j2 - 1]; rx[j2 - 1] = t0;
        t0 = ry[j2]; ry[j2] = ry[j2 - 1]; ry[j2 - 1] = t0;
        t0 = rz[j2]; rz[j2] = rz[j2 - 1]; rz[j2 - 1] = t0;
      }
    }
  }

  double sum[10], ss[10];
#pragma unroll
  for (int c = 0; c < 10; ++c) { sum[c] = 0.0; ss[c] = 0.0; }

  float sgn = 1.0f;
#pragma unroll
  for (int t = 0; t < K_; ++t) {
    int u = (t + 1 == K_) ? 0 : t + 1;
    float cx = 0.5f * (rx[t] + rx[u]);
    float cy = 0.5f * (ry[t] + ry[u]);
    float cz = 0.5f * (rz[t] + rz[u]);
    float nx = ry[t] * rz[u] - rz[t] * ry[u];
    float ny = rz[t] * rx[u] - rx[t] * rz[u];
    float nz = rx[t] * ry[u] - ry[t] * rx[u];
    float nrm = sqrtf(nx * nx + ny * ny + nz * nz) + 1e-6f;
    nx /= nrm; ny /= nrm; nz /= nrm;
    if (t == 0) sgn = (nx > 0.0f) ? 1.0f : -1.0f;
    nx *= sgn; ny *= sgn; nz *= sgn;
    float pos = (nx * cx + ny * cy + nz * cz) / 1.7320508075688772f;

    float fv[7] = {cx, cy, cz, nx, ny, nz, pos};
    size_t row = ((size_t)p * K_ + t) * 10;
#pragma unroll
    for (int c = 0; c < 10; ++c) {
      float h = b1[c];
#pragma unroll
      for (int r = 0; r < 7; ++r) h = fmaf(fv[r], W1[r * 10 + c], h);
      h1[row + c] = h;
      double hd = (double)h;
      sum[c] += hd;
      ss[c] += hd * hd;
    }
  }

#pragma unroll
  for (int c = 0; c < 10; ++c) {
    double a = sum[c];
#pragma unroll
    for (int off = 32; off > 0; off >>= 1) a += __shfl_down(a, off);
    if (threadIdx.x == 0) part1[(size_t)blockIdx.x * 20 + c] = a;
    double qq = ss[c];
#pragma unroll
    for (int off = 32; off > 0; off >>= 1) qq += __shfl_down(qq, off);
    if (threadIdx.x == 0) part1[(size_t)blockIdx.x * 20 + 10 + c] = qq;
  }
}

// ---------------- K3: reduce partials -> mu[10], rsqrt(var+eps)[10] -------------
__launch_bounds__(256)
__global__ void k_reduce(const double* __restrict__ part, int nblk,
                         float* __restrict__ MR) {
  __shared__ double acc[256];
  int tid = threadIdx.x;
  int c = tid % 20;
  int ch = tid / 20;
  double s = 0.0;
  if (ch < 12) {
    for (int i = ch; i < nblk; i += 12) s += part[(size_t)i * 20 + c];
  }
  acc[tid] = s;
  __syncthreads();
  if (tid < 20) {
    double t = 0.0;
#pragma unroll
    for (int k2 = 0; k2 < 12; ++k2) t += acc[k2 * 20 + tid];
    acc[tid] = t;
  }
  __syncthreads();
  if (tid < 10) {
    double mu = acc[tid] / (double)NROWS;
    double var = acc[10 + tid] / (double)NROWS - mu * mu;
    MR[tid] = (float)mu;
    MR[10 + tid] = (float)(1.0 / sqrt(var + 1e-5));
  }
}

// ---------------- K4: bn1 + relu + @W2+b2 -> h2, stats partials -----------------
__launch_bounds__(256)
__global__ void k_mlp2(const float* __restrict__ h1, const float* __restrict__ MR1,
                       const float* __restrict__ g1, const float* __restrict__ be1,
                       const float* __restrict__ W2, const float* __restrict__ b2,
                       float* __restrict__ h2, double* __restrict__ part2) {
  int r = blockIdx.x * 256 + threadIdx.x;
  float v[10];
#pragma unroll
  for (int c = 0; c < 10; ++c) {
    float h = h1[(size_t)r * 10 + c];
    float z = g1[c] * (h - MR1[c]) * MR1[10 + c] + be1[c];
    v[c] = z > 0.0f ? z : 0.0f;
  }
  float o[10];
#pragma unroll
  for (int c = 0; c < 10; ++c) {
    float h = b2[c];
#pragma unroll
    for (int t = 0; t < 10; ++t) h = fmaf(v[t], W2[t * 10 + c], h);
    o[c] = h;
    h2[(size_t)r * 10 + c] = h;
  }

  __shared__ double sred[4][20];
  int lane = threadIdx.x & 63, wv = threadIdx.x >> 6;
#pragma unroll
  for (int c = 0; c < 10; ++c) {
    double a = (double)o[c];
#pragma unroll
    for (int off = 32; off > 0; off >>= 1) a += __shfl_down(a, off);
    if (lane == 0) sred[wv][c] = a;
    double qq = (double)o[c] * (double)o[c];
#pragma unroll
    for (int off = 32; off > 0; off >>= 1) qq += __shfl_down(qq, off);
    if (lane == 0) sred[wv][10 + c] = qq;
  }
  __syncthreads();
  if (threadIdx.x < 20) {
    part2[(size_t)blockIdx.x * 20 + threadIdx.x] =
        sred[0][threadIdx.x] + sred[1][threadIdx.x] +
        sred[2][threadIdx.x] + sred[3][threadIdx.x];
  }
}

// ---------------- K5: bn2 + relu + max over k -> out ----------------------------
__launch_bounds__(256)
__global__ void k_out(const float* __restrict__ h2, const float* __restrict__ MR2,
                      const float* __restrict__ g2, const float* __restrict__ be2,
                      float* __restrict__ out) {
  int p = blockIdx.x * 256 + threadIdx.x;
  if (p >= NPTS) return;
#pragma unroll
  for (int c = 0; c < 10; ++c) {
    float m = -FLT_MAX;
#pragma unroll
    for (int j = 0; j < K_; ++j) {
      float h = h2[((size_t)p * K_ + j) * 10 + c];
      float z = g2[c] * (h - MR2[c]) * MR2[10 + c] + be2[c];
      z = z > 0.0f ? z : 0.0f;
      m = fmaxf(m, z);
    }
    out[(size_t)p * 10 + c] = m;
  }
}

extern "C" void kernel_launch(void* const* d_in, const int* in_sizes, int n_in,
                              void* d_out, int out_size, void* d_ws, size_t ws_size,
                              hipStream_t stream) {
  (void)in_sizes; (void)n_in; (void)out_size; (void)ws_size;
  const float* x  = (const float*)d_in[0];
  const float* W1 = (const float*)d_in[1];
  const float* b1 = (const float*)d_in[2];
  const float* g1 = (const float*)d_in[3];
  const float* be1= (const float*)d_in[4];
  const float* W2 = (const float*)d_in[5];
  const float* b2 = (const float*)d_in[6];
  const float* g2 = (const float*)d_in[7];
  const float* be2= (const float*)d_in[8];
  float* out = (float*)d_out;

  char* base = (char*)d_ws;
  float4* P  = (float4*)base;                       // 512 KB
  float*  h1 = (float*)(base + (size_t)NPTS * 16);  // 11.8 MB
  char*   C  = (char*)(h1 + (size_t)NROWS * 10);
  float*  pbd = (float*)C;                          // 9.44 MB
  int*    pbi = (int*)(C + (size_t)NPTS * SPLIT * K_ * 4);  // 9.44 MB
  // h2/part2 alias the pbd/pbi region (pbd/pbi fully consumed by k_feat
  // before k_mlp2 writes h2)
  float*  h2 = (float*)C;                           // 11.8 MB
  double* part2 = (double*)(C + 12 * 1024 * 1024);  // 184 KB, within C's 18.9MB
  char*   tail = C + (size_t)NPTS * SPLIT * K_ * 8;
  float*  MR1 = (float*)tail;
  float*  MR2 = MR1 + 32;
  double* part1 = (double*)(MR2 + 32);              // 512*20 doubles

  k_pack<<<(NPTS + 255) / 256, 256, 0, stream>>>(x, P);
  k_knn_part<<<PT_BLOCKS * SPLIT, 64, 0, stream>>>(P, pbd, pbi);
  k_feat<<<PT_BLOCKS, 64, 0, stream>>>(P, pbd, pbi, W1, b1, h1, part1);
  k_reduce<<<1, 256, 0, stream>>>(part1, PT_BLOCKS, MR1);
  k_mlp2<<<MLP_BLOCKS, 256, 0, stream>>>(h1, MR1, g1, be1, W2, b2, h2, part2);
  k_reduce<<<1, 256, 0, stream>>>(part2, MLP_BLOCKS, MR2);
  k_out<<<(NPTS + 255) / 256, 256, 0, stream>>>(h2, MR2, g2, be2, out);
}

// Round 4
// 446.652 us; speedup vs baseline: 4.4783x; 1.2458x over previous
//
#include <hip/hip_runtime.h>
#include <math.h>
#include <float.h>
#include <stdint.h>

#define B_ 4
#define N_ 8192
#define K_ 9
#define NPTS (B_ * N_)           // 32768
#define NROWS (NPTS * K_)        // 294912
#define SPLIT 8
#define CHUNK (N_ / SPLIT)       // 1024
#define NGROUP 32
#define GSIZE (CHUNK / NGROUP)   // 32
#define PT_BLOCKS (NPTS / 64)    // 512
#define MLP_BLOCKS (NROWS / 256) // 1152

// ---------------- K0: pack x -> float4 AoS (x,y,z,|x|^2) + SoA X,Y,Z,S ---------
__launch_bounds__(256)
__global__ void k_pack(const float* __restrict__ x, float4* __restrict__ P,
                       float* __restrict__ X, float* __restrict__ Y,
                       float* __restrict__ Z, float* __restrict__ S) {
  int i = blockIdx.x * 256 + threadIdx.x;
  if (i >= NPTS) return;
  float a = x[3 * i], b = x[3 * i + 1], c = x[3 * i + 2];
  float s = a * a + b * b + c * c;
  P[i] = make_float4(a, b, c, s);
  X[i] = a; Y[i] = b; Z[i] = c; S[i] = s;
}

// ---------------- K1: two-level exact top-9 per 1024-chunk ----------------------
// Scan: per-group (32 cand) running min — 3 VALU/candidate, branchless.
// Extract: 9 rounds of lex-min over 32 group records + refill winning group.
__launch_bounds__(64, 3)
__global__ void k_knn2(const float4* __restrict__ P,
                       const float* __restrict__ X, const float* __restrict__ Y,
                       const float* __restrict__ Z, const float* __restrict__ S,
                       float* __restrict__ pbd, int* __restrict__ pbi) {
  int pt_blk = blockIdx.x >> 3;          // / SPLIT
  int s = blockIdx.x & (SPLIT - 1);
  int p = pt_blk * 64 + threadIdx.x;
  int b = p >> 13;
  int n = p & (N_ - 1);
  const float4* __restrict__ Pb = P + b * N_;
  const float* __restrict__ Xb = X + b * N_;
  const float* __restrict__ Yb = Y + b * N_;
  const float* __restrict__ Zb = Z + b * N_;
  const float* __restrict__ Sb = S + b * N_;

  float4 q = Pb[n];
  int j0 = s * CHUNK;

  float gd[NGROUP];
  int gi[NGROUP];

  // ---- scan phase: per-group min (strict <, ascending index => lex-correct) ----
#pragma unroll
  for (int g = 0; g < NGROUP; ++g) {
    int jg = j0 + g * GSIZE;
    float bgd = FLT_MAX;
    int bgi = 0;
#pragma clang loop unroll(disable)
    for (int jj = 0; jj < GSIZE; jj += 4) {
      int j = jg + jj;
      float4 c0 = Pb[j];
      float4 c1 = Pb[j + 1];
      float4 c2 = Pb[j + 2];
      float4 c3 = Pb[j + 3];
      float d0 = (q.w + c0.w) - 2.0f * (q.x * c0.x + q.y * c0.y + q.z * c0.z);
      float d1 = (q.w + c1.w) - 2.0f * (q.x * c1.x + q.y * c1.y + q.z * c1.z);
      float d2 = (q.w + c2.w) - 2.0f * (q.x * c2.x + q.y * c2.y + q.z * c2.z);
      float d3 = (q.w + c3.w) - 2.0f * (q.x * c3.x + q.y * c3.y + q.z * c3.z);
      d0 = (j + 0 == n) ? FLT_MAX : d0;
      d1 = (j + 1 == n) ? FLT_MAX : d1;
      d2 = (j + 2 == n) ? FLT_MAX : d2;
      d3 = (j + 3 == n) ? FLT_MAX : d3;
      bool l0 = d0 < bgd; bgd = l0 ? d0 : bgd; bgi = l0 ? (j + 0) : bgi;
      bool l1 = d1 < bgd; bgd = l1 ? d1 : bgd; bgi = l1 ? (j + 1) : bgi;
      bool l2 = d2 < bgd; bgd = l2 ? d2 : bgd; bgi = l2 ? (j + 2) : bgi;
      bool l3 = d3 < bgd; bgd = l3 ? d3 : bgd; bgi = l3 ? (j + 3) : bgi;
    }
    gd[g] = bgd;
    gi[g] = bgi;
  }

  // ---- extraction phase: 9 rounds --------------------------------------------
  float* ob = pbd + ((size_t)p * SPLIT + s) * K_;
  int*   oi = pbi + ((size_t)p * SPLIT + s) * K_;

#pragma clang loop unroll(disable)
  for (int r = 0; r < K_; ++r) {
    // lexicographic min over the 32 records (keys (d,i) are all distinct)
    float wd = gd[0]; int wi = gi[0]; int wg = 0;
#pragma unroll
    for (int g = 1; g < NGROUP; ++g) {
      bool lt = (gd[g] < wd) | ((gd[g] == wd) & (gi[g] < wi));
      wd = lt ? gd[g] : wd;
      wi = lt ? gi[g] : wi;
      wg = lt ? g : wg;
    }
    ob[r] = wd;
    oi[r] = wi;

    // refill group wg: min over its candidates with key strictly > (wd, wi)
    int base = j0 + wg * GSIZE;   // per-lane; multiple of 4 -> aligned float4
    float nd = FLT_MAX; int ni = 0;
#pragma clang loop unroll(disable)
    for (int jj = 0; jj < GSIZE; jj += 4) {
      int j = base + jj;
      float4 xv = *(const float4*)(Xb + j);
      float4 yv = *(const float4*)(Yb + j);
      float4 zv = *(const float4*)(Zb + j);
      float4 sv = *(const float4*)(Sb + j);
      float d0 = (q.w + sv.x) - 2.0f * (q.x * xv.x + q.y * yv.x + q.z * zv.x);
      float d1 = (q.w + sv.y) - 2.0f * (q.x * xv.y + q.y * yv.y + q.z * zv.y);
      float d2 = (q.w + sv.z) - 2.0f * (q.x * xv.z + q.y * yv.z + q.z * zv.z);
      float d3 = (q.w + sv.w) - 2.0f * (q.x * xv.w + q.y * yv.w + q.z * zv.w);
      // exclude self
      d0 = (j + 0 == n) ? FLT_MAX : d0;
      d1 = (j + 1 == n) ? FLT_MAX : d1;
      d2 = (j + 2 == n) ? FLT_MAX : d2;
      d3 = (j + 3 == n) ? FLT_MAX : d3;
      // keep only keys strictly greater than the extracted key
      bool k0 = (d0 > wd) | ((d0 == wd) & ((j + 0) > wi));
      bool k1 = (d1 > wd) | ((d1 == wd) & ((j + 1) > wi));
      bool k2 = (d2 > wd) | ((d2 == wd) & ((j + 2) > wi));
      bool k3 = (d3 > wd) | ((d3 == wd) & ((j + 3) > wi));
      d0 = k0 ? d0 : FLT_MAX;
      d1 = k1 ? d1 : FLT_MAX;
      d2 = k2 ? d2 : FLT_MAX;
      d3 = k3 ? d3 : FLT_MAX;
      bool l0 = d0 < nd; nd = l0 ? d0 : nd; ni = l0 ? (j + 0) : ni;
      bool l1 = d1 < nd; nd = l1 ? d1 : nd; ni = l1 ? (j + 1) : ni;
      bool l2 = d2 < nd; nd = l2 ? d2 : nd; ni = l2 ? (j + 2) : ni;
      bool l3 = d3 < nd; nd = l3 ? d3 : nd; ni = l3 ? (j + 3) : ni;
    }
    // write back into the winning group's record
#pragma unroll
    for (int g = 0; g < NGROUP; ++g) {
      bool m = (g == wg);
      gd[g] = m ? nd : gd[g];
      gi[g] = m ? ni : gi[g];
    }
  }
}

// Register-resident sorted top-9 insert (used by the merge in k_feat).
#define LVL(bdv, biv)                                                     \
  { bool lt = cd < (bdv); float td = (bdv); int ti = (biv);               \
    (bdv) = lt ? cd : (bdv); (biv) = lt ? ci : (biv);                     \
    cd = lt ? td : cd; ci = lt ? ti : ci; }

#define INS9ALL()                                                         \
  LVL(b0d, b0i) LVL(b1d, b1i) LVL(b2d, b2i) LVL(b3d, b3i) LVL(b4d, b4i)  \
  LVL(b5d, b5i) LVL(b6d, b6i) LVL(b7d, b7i) LVL(b8d, b8i)

#define TOP9_DECL()                                                       \
  float b0d = FLT_MAX, b1d = FLT_MAX, b2d = FLT_MAX, b3d = FLT_MAX,       \
        b4d = FLT_MAX, b5d = FLT_MAX, b6d = FLT_MAX, b7d = FLT_MAX,       \
        b8d = FLT_MAX;                                                    \
  int b0i = 0, b1i = 0, b2i = 0, b3i = 0, b4i = 0, b5i = 0, b6i = 0,      \
      b7i = 0, b8i = 0;

// ---------------- K2: merge partials + geometric features + h1 + stats ----------
__launch_bounds__(64)
__global__ void k_feat(const float4* __restrict__ P,
                       const float* __restrict__ pbd, const int* __restrict__ pbi,
                       const float* __restrict__ W1, const float* __restrict__ b1,
                       float* __restrict__ h1, double* __restrict__ part1) {
  int p = blockIdx.x * 64 + threadIdx.x;
  int b = p >> 13;
  int n = p & (N_ - 1);
  const float4* __restrict__ Pb = P + b * N_;
  float4 q = Pb[n];

  // merge 8 sorted partial lists (ascending chunk order = ascending index order
  // -> stable strict-< insertion reproduces top_k tie-breaking)
  TOP9_DECL();
  const float* mb = pbd + (size_t)p * (SPLIT * K_);
  const int*   ib = pbi + (size_t)p * (SPLIT * K_);
  for (int s = 0; s < SPLIT * K_; ++s) {
    float cd = mb[s];
    if (cd < b8d) { int ci = ib[s]; INS9ALL(); }
  }

  int bi[K_] = {b0i, b1i, b2i, b3i, b4i, b5i, b6i, b7i, b8i};

  // relative vectors in distance order (reference pre-sort order)
  float rx[K_], ry[K_], rz[K_], ph[K_];
#pragma unroll
  for (int t = 0; t < K_; ++t) {
    float4 m = Pb[bi[t]];
    rx[t] = m.x - q.x;
    ry[t] = m.y - q.y;
    rz[t] = m.z - q.z;
    ph[t] = atan2f(ry[t], rx[t]);
  }

  // stable insertion sort ascending by phi
#pragma unroll
  for (int i = 1; i < K_; ++i) {
#pragma unroll
    for (int j2 = i; j2 > 0; --j2) {
      if (ph[j2] < ph[j2 - 1]) {
        float t0;
        t0 = ph[j2]; ph[j2] = ph[j2 - 1]; ph[j2 - 1] = t0;
        t0 = rx[j2]; rx[j2] = rx[j2 - 1]; rx[j2 - 1] = t0;
        t0 = ry[j2]; ry[j2] = ry[j2 - 1]; ry[j2 - 1] = t0;
        t0 = rz[j2]; rz[j2] = rz[j2 - 1]; rz[j2 - 1] = t0;
      }
    }
  }

  double sum[10], ss[10];
#pragma unroll
  for (int c = 0; c < 10; ++c) { sum[c] = 0.0; ss[c] = 0.0; }

  float sgn = 1.0f;
#pragma unroll
  for (int t = 0; t < K_; ++t) {
    int u = (t + 1 == K_) ? 0 : t + 1;
    float cx = 0.5f * (rx[t] + rx[u]);
    float cy = 0.5f * (ry[t] + ry[u]);
    float cz = 0.5f * (rz[t] + rz[u]);
    float nx = ry[t] * rz[u] - rz[t] * ry[u];
    float ny = rz[t] * rx[u] - rx[t] * rz[u];
    float nz = rx[t] * ry[u] - ry[t] * rx[u];
    float nrm = sqrtf(nx * nx + ny * ny + nz * nz) + 1e-6f;
    nx /= nrm; ny /= nrm; nz /= nrm;
    if (t == 0) sgn = (nx > 0.0f) ? 1.0f : -1.0f;
    nx *= sgn; ny *= sgn; nz *= sgn;
    float pos = (nx * cx + ny * cy + nz * cz) / 1.7320508075688772f;

    float fv[7] = {cx, cy, cz, nx, ny, nz, pos};
    size_t row = ((size_t)p * K_ + t) * 10;
#pragma unroll
    for (int c = 0; c < 10; ++c) {
      float h = b1[c];
#pragma unroll
      for (int r = 0; r < 7; ++r) h = fmaf(fv[r], W1[r * 10 + c], h);
      h1[row + c] = h;
      double hd = (double)h;
      sum[c] += hd;
      ss[c] += hd * hd;
    }
  }

#pragma unroll
  for (int c = 0; c < 10; ++c) {
    double a = sum[c];
#pragma unroll
    for (int off = 32; off > 0; off >>= 1) a += __shfl_down(a, off);
    if (threadIdx.x == 0) part1[(size_t)blockIdx.x * 20 + c] = a;
    double qq = ss[c];
#pragma unroll
    for (int off = 32; off > 0; off >>= 1) qq += __shfl_down(qq, off);
    if (threadIdx.x == 0) part1[(size_t)blockIdx.x * 20 + 10 + c] = qq;
  }
}

// ---------------- K3: reduce partials -> mu[10], rsqrt(var+eps)[10] -------------
__launch_bounds__(256)
__global__ void k_reduce(const double* __restrict__ part, int nblk,
                         float* __restrict__ MR) {
  __shared__ double acc[256];
  int tid = threadIdx.x;
  int c = tid % 20;
  int ch = tid / 20;
  double s = 0.0;
  if (ch < 12) {
    for (int i = ch; i < nblk; i += 12) s += part[(size_t)i * 20 + c];
  }
  acc[tid] = s;
  __syncthreads();
  if (tid < 20) {
    double t = 0.0;
#pragma unroll
    for (int k2 = 0; k2 < 12; ++k2) t += acc[k2 * 20 + tid];
    acc[tid] = t;
  }
  __syncthreads();
  if (tid < 10) {
    double mu = acc[tid] / (double)NROWS;
    double var = acc[10 + tid] / (double)NROWS - mu * mu;
    MR[tid] = (float)mu;
    MR[10 + tid] = (float)(1.0 / sqrt(var + 1e-5));
  }
}

// ---------------- K4: bn1 + relu + @W2+b2 -> h2, stats partials -----------------
__launch_bounds__(256)
__global__ void k_mlp2(const float* __restrict__ h1, const float* __restrict__ MR1,
                       const float* __restrict__ g1, const float* __restrict__ be1,
                       const float* __restrict__ W2, const float* __restrict__ b2,
                       float* __restrict__ h2, double* __restrict__ part2) {
  int r = blockIdx.x * 256 + threadIdx.x;
  float v[10];
#pragma unroll
  for (int c = 0; c < 10; ++c) {
    float h = h1[(size_t)r * 10 + c];
    float z = g1[c] * (h - MR1[c]) * MR1[10 + c] + be1[c];
    v[c] = z > 0.0f ? z : 0.0f;
  }
  float o[10];
#pragma unroll
  for (int c = 0; c < 10; ++c) {
    float h = b2[c];
#pragma unroll
    for (int t = 0; t < 10; ++t) h = fmaf(v[t], W2[t * 10 + c], h);
    o[c] = h;
    h2[(size_t)r * 10 + c] = h;
  }

  __shared__ double sred[4][20];
  int lane = threadIdx.x & 63, wv = threadIdx.x >> 6;
#pragma unroll
  for (int c = 0; c < 10; ++c) {
    double a = (double)o[c];
#pragma unroll
    for (int off = 32; off > 0; off >>= 1) a += __shfl_down(a, off);
    if (lane == 0) sred[wv][c] = a;
    double qq = (double)o[c] * (double)o[c];
#pragma unroll
    for (int off = 32; off > 0; off >>= 1) qq += __shfl_down(qq, off);
    if (lane == 0) sred[wv][10 + c] = qq;
  }
  __syncthreads();
  if (threadIdx.x < 20) {
    part2[(size_t)blockIdx.x * 20 + threadIdx.x] =
        sred[0][threadIdx.x] + sred[1][threadIdx.x] +
        sred[2][threadIdx.x] + sred[3][threadIdx.x];
  }
}

// ---------------- K5: bn2 + relu + max over k -> out ----------------------------
__launch_bounds__(256)
__global__ void k_out(const float* __restrict__ h2, const float* __restrict__ MR2,
                      const float* __restrict__ g2, const float* __restrict__ be2,
                      float* __restrict__ out) {
  int p = blockIdx.x * 256 + threadIdx.x;
  if (p >= NPTS) return;
#pragma unroll
  for (int c = 0; c < 10; ++c) {
    float m = -FLT_MAX;
#pragma unroll
    for (int j = 0; j < K_; ++j) {
      float h = h2[((size_t)p * K_ + j) * 10 + c];
      float z = g2[c] * (h - MR2[c]) * MR2[10 + c] + be2[c];
      z = z > 0.0f ? z : 0.0f;
      m = fmaxf(m, z);
    }
    out[(size_t)p * 10 + c] = m;
  }
}

extern "C" void kernel_launch(void* const* d_in, const int* in_sizes, int n_in,
                              void* d_out, int out_size, void* d_ws, size_t ws_size,
                              hipStream_t stream) {
  (void)in_sizes; (void)n_in; (void)out_size; (void)ws_size;
  const float* x  = (const float*)d_in[0];
  const float* W1 = (const float*)d_in[1];
  const float* b1 = (const float*)d_in[2];
  const float* g1 = (const float*)d_in[3];
  const float* be1= (const float*)d_in[4];
  const float* W2 = (const float*)d_in[5];
  const float* b2 = (const float*)d_in[6];
  const float* g2 = (const float*)d_in[7];
  const float* be2= (const float*)d_in[8];
  float* out = (float*)d_out;

  char* base = (char*)d_ws;
  float4* P  = (float4*)base;                        // 512 KB
  float*  X  = (float*)(base + (size_t)NPTS * 16);   // 128 KB each
  float*  Y  = X + NPTS;
  float*  Z  = Y + NPTS;
  float*  S  = Z + NPTS;
  float*  h1 = S + NPTS;                             // NROWS*10 floats, 11.8 MB
  char*   C  = (char*)(h1 + (size_t)NROWS * 10);
  float*  pbd = (float*)C;                           // 9.44 MB
  int*    pbi = (int*)(C + (size_t)NPTS * SPLIT * K_ * 4);  // 9.44 MB
  // h2/part2 alias the pbd/pbi region (pbd/pbi fully consumed by k_feat
  // before k_mlp2 writes h2)
  float*  h2 = (float*)C;                            // 11.8 MB
  double* part2 = (double*)(C + 12 * 1024 * 1024);   // 184 KB, within C's 18.9MB
  char*   tail = C + (size_t)NPTS * SPLIT * K_ * 8;
  float*  MR1 = (float*)tail;
  float*  MR2 = MR1 + 32;
  double* part1 = (double*)(MR2 + 32);               // 512*20 doubles

  k_pack<<<(NPTS + 255) / 256, 256, 0, stream>>>(x, P, X, Y, Z, S);
  k_knn2<<<PT_BLOCKS * SPLIT, 64, 0, stream>>>(P, X, Y, Z, S, pbd, pbi);
  k_feat<<<PT_BLOCKS, 64, 0, stream>>>(P, pbd, pbi, W1, b1, h1, part1);
  k_reduce<<<1, 256, 0, stream>>>(part1, PT_BLOCKS, MR1);
  k_mlp2<<<MLP_BLOCKS, 256, 0, stream>>>(h1, MR1, g1, be1, W2, b2, h2, part2);
  k_reduce<<<1, 256, 0, stream>>>(part2, MLP_BLOCKS, MR2);
  k_out<<<(NPTS + 255) / 256, 256, 0, stream>>>(h2, MR2, g2, be2, out);
}